// Round 1
// 509.018 us; speedup vs baseline: 1.0727x; 1.0727x over previous
//
#include <hip/hip_runtime.h>
#include <hip/hip_bf16.h>

// ReadUnit: B=512, D=512, N=196
// rai[b,n] = sum_d p[b,d]*kbp[b,d,n] + q[b,d]*kb[b,d,n]   (+const_b, softmax-invariant)
//   p = (ms@Wmem^T + bmem) * v[:, :D],  q = v[:, D:],  v = (ctrl*Wattn) @ Wcat
// out[b,d] = sum_n softmax(rai)[n] * kb[b,d,n]
//
// Two-pass: k_rai streams kb+kbp once (dense float4 rows, kbp nontemporal so L3
// keeps kb), k_out re-reads kb (reverse batch order to hit L3 tail).
// v2: both streaming kernels were latency-bound at 16 (k_rai) / 8 (k_out)
// waves/CU (Occupancy 33%, VALUBusy 3%, hbm 22%). Split d-range 4-way in each:
// 2048 blocks = 8 blocks/CU = 32 waves/CU (occupancy cap with VGPR<=64).

constexpr int D = 512;
constexpr int N = 196;
constexpr int NF4 = 49;  // N/4

using f4 = __attribute__((ext_vector_type(4))) float;

// ---------------- Phase A: two small fp32 GEMMs into workspace ----------------
__global__ __launch_bounds__(256) void phase_a(
    const float* __restrict__ ms, const float* __restrict__ ctrl,
    const float* __restrict__ Wmem, const float* __restrict__ bmem,
    const float* __restrict__ Wcat, const float* __restrict__ Wattn,
    float* __restrict__ mem_ws, float* __restrict__ v_ws)
{
    constexpr int PAD = 68;
    __shared__ float As[16 * PAD];
    __shared__ float Bs[16 * PAD];

    const int bid = blockIdx.x;
    const int t   = threadIdx.x;
    const int tx  = t & 15, ty = t >> 4;

    const bool g1 = (bid < 64);
    int tile_m, tile_n;
    if (g1) { tile_m = (bid >> 3) * 64; tile_n = (bid & 7) * 64; }
    else    { int bb = bid - 64; tile_m = (bb >> 4) * 64; tile_n = (bb & 15) * 64; }

    float acc[4][4] = {};

    for (int k0 = 0; k0 < 512; k0 += 16) {
        {
            const int k = t & 15;
            const int mbase = t >> 4;
#pragma unroll
            for (int r = 0; r < 4; r++) {
                const int m = mbase + 16 * r;
                const int row = tile_m + m;
                float a;
                if (g1) a = ms[row * 512 + k0 + k];
                else    a = ctrl[row * 512 + k0 + k] * Wattn[k0 + k];
                As[k * PAD + m] = a;
            }
        }
        if (g1) {
            const int k = t & 15;
            const int nbase = t >> 4;
#pragma unroll
            for (int r = 0; r < 4; r++) {
                const int n = nbase + 16 * r;
                Bs[k * PAD + n] = Wmem[(tile_n + n) * 512 + k0 + k];
            }
        } else {
            const int n = t & 63;
            const int kbase = t >> 6;
#pragma unroll
            for (int r = 0; r < 4; r++) {
                const int k = kbase + 4 * r;
                Bs[k * PAD + n] = Wcat[(k0 + k) * 1024 + tile_n + n];
            }
        }
        __syncthreads();
#pragma unroll
        for (int k = 0; k < 16; k++) {
            const float4 av = *reinterpret_cast<const float4*>(&As[k * PAD + ty * 4]);
            const float4 bv = *reinterpret_cast<const float4*>(&Bs[k * PAD + tx * 4]);
            const float a[4] = {av.x, av.y, av.z, av.w};
            const float bb[4] = {bv.x, bv.y, bv.z, bv.w};
#pragma unroll
            for (int i = 0; i < 4; i++)
#pragma unroll
                for (int j = 0; j < 4; j++)
                    acc[i][j] += a[i] * bb[j];
        }
        __syncthreads();
    }

    if (g1) {
#pragma unroll
        for (int i = 0; i < 4; i++) {
            const int row = tile_m + ty * 4 + i;
#pragma unroll
            for (int j = 0; j < 4; j++) {
                const int col = tile_n + tx * 4 + j;
                mem_ws[row * 512 + col] = acc[i][j] + bmem[col];
            }
        }
    } else {
#pragma unroll
        for (int i = 0; i < 4; i++) {
            const int row = tile_m + ty * 4 + i;
#pragma unroll
            for (int j = 0; j < 4; j++) {
                const int col = tile_n + tx * 4 + j;
                v_ws[row * 1024 + col] = acc[i][j];
            }
        }
    }
}

// ---------------- K1: rai partials, one pass over kb+kbp, fully coalesced ----------------
// 2048 blocks: (b, d-quarter). Lane l<49 owns float4-column l; each wave-instr reads
// one contiguous 784B row. kbp is dead after this kernel -> nontemporal.
// 8 blocks/CU -> 32 waves/CU (VGPR 36 permits 8 waves/SIMD).
__global__ __launch_bounds__(256, 8) void k_rai(
    const f4* __restrict__ kb, const f4* __restrict__ kbp,
    const float* __restrict__ mem_ws, const float* __restrict__ v_ws,
    float* __restrict__ rai_ws)
{
    __shared__ float p_s[128];
    __shared__ float q_s[128];
    __shared__ float part[4][200];

    const int bid = blockIdx.x;
    const int b   = bid >> 2;
    const int s   = bid & 3;
    const int d0  = s * 128;
    const int t    = threadIdx.x;
    const int lane = t & 63;
    const int w    = t >> 6;

    if (t < 128) {
        const int d = d0 + t;
        p_s[t] = mem_ws[b * D + d] * v_ws[b * 2 * D + d];
        q_s[t] = v_ws[b * 2 * D + D + d];
    }
    __syncthreads();

    const int lc = (lane < NF4) ? lane : (NF4 - 1);  // lanes 49..63 duplicate col 48
    const f4* kb_b  = kb  + (size_t)b * (D * NF4);
    const f4* kbp_b = kbp + (size_t)b * (D * NF4);

    float a0 = 0.f, a1 = 0.f, a2 = 0.f, a3 = 0.f;
    const int dw = d0 + w * 32;  // each wave: 32 contiguous rows
#pragma unroll 4
    for (int r = 0; r < 32; r++) {
        const int d = dw + r;
        const f4 vp = __builtin_nontemporal_load(&kbp_b[(size_t)d * NF4 + lc]);
        const f4 vk = kb_b[(size_t)d * NF4 + lc];
        const float pd = p_s[d - d0];
        const float qd = q_s[d - d0];
        a0 += pd * vp.x + qd * vk.x;
        a1 += pd * vp.y + qd * vk.y;
        a2 += pd * vp.z + qd * vk.z;
        a3 += pd * vp.w + qd * vk.w;
    }

    if (lane < NF4) {
        part[w][4 * lane + 0] = a0;
        part[w][4 * lane + 1] = a1;
        part[w][4 * lane + 2] = a2;
        part[w][4 * lane + 3] = a3;
    }
    __syncthreads();

    if (t < N) {
        const float r = part[0][t] + part[1][t] + part[2][t] + part[3][t];
        rai_ws[(size_t)(b * 4 + s) * N + t] = r;
    }
}

// ---------------- K2: softmax + weighted sum, one pass over kb ----------------
// 2048 blocks: (b, d-quarter), reverse batch order so k_rai's L3 tail is hot.
// Each block recomputes the (cheap) softmax from the 4 rai partials.
__global__ __launch_bounds__(256, 8) void k_out(
    const f4* __restrict__ kb, const float* __restrict__ rai_ws,
    float* __restrict__ out)
{
    __shared__ float w_s[N];
    __shared__ float red[4];
    __shared__ float out_s[128];

    const int bid = blockIdx.x;
    const int b   = 511 - (bid >> 2);
    const int h   = bid & 3;
    const int d0  = h * 128;
    const int t    = threadIdx.x;
    const int lane = t & 63;
    const int w    = t >> 6;

    float e = 0.f;
    if (t < N) {
        const float* rb = rai_ws + (size_t)b * 4 * N;
        const float r = rb[t] + rb[N + t] + rb[2 * N + t] + rb[3 * N + t];
        e = __expf(r);           // rai is O(+-10): no max-subtraction needed in fp32
        w_s[t] = e;
    }
    float ssum = e;
#pragma unroll
    for (int m = 32; m; m >>= 1) ssum += __shfl_xor(ssum, m, 64);
    if (lane == 0) red[w] = ssum;
    __syncthreads();

    const float inv = 1.0f / (red[0] + red[1] + red[2] + red[3]);

    f4 wv = {0.f, 0.f, 0.f, 0.f};
    if (lane < NF4) {            // lanes >=49: wv=0 -> contribute 0 to reduction
        wv.x = w_s[4 * lane + 0] * inv;
        wv.y = w_s[4 * lane + 1] * inv;
        wv.z = w_s[4 * lane + 2] * inv;
        wv.w = w_s[4 * lane + 3] * inv;
    }

    const int lc = (lane < NF4) ? lane : (NF4 - 1);
    const f4* kb_b = kb + (size_t)b * (D * NF4);
    const int dw = d0 + w * 32;  // each wave: 32 contiguous rows
#pragma unroll 4
    for (int r = 0; r < 32; r++) {
        const int d = dw + r;
        const f4 v = kb_b[(size_t)d * NF4 + lc];
        float sc = v.x * wv.x + v.y * wv.y + v.z * wv.z + v.w * wv.w;
#pragma unroll
        for (int m = 32; m; m >>= 1) sc += __shfl_xor(sc, m, 64);
        if (lane == 0) out_s[d - d0] = sc;
    }
    __syncthreads();

    if (t < 128) out[(size_t)b * D + d0 + t] = out_s[t];
}

extern "C" void kernel_launch(void* const* d_in, const int* in_sizes, int n_in,
                              void* d_out, int out_size, void* d_ws, size_t ws_size,
                              hipStream_t stream) {
    const float* ms    = (const float*)d_in[0];
    const float* kb    = (const float*)d_in[1];
    const float* ctrl  = (const float*)d_in[2];
    const float* kbp   = (const float*)d_in[3];
    const float* Wmem  = (const float*)d_in[4];
    const float* bmem  = (const float*)d_in[5];
    const float* Wcat  = (const float*)d_in[6];
    const float* Wattn = (const float*)d_in[8];

    float* mem_ws = (float*)d_ws;                 // 512*512
    float* v_ws   = mem_ws + 512 * 512;           // 512*1024
    float* rai_ws = v_ws + 512 * 1024;            // 512*4*196

    phase_a<<<192, 256, 0, stream>>>(ms, ctrl, Wmem, bmem, Wcat, Wattn, mem_ws, v_ws);
    k_rai<<<2048, 256, 0, stream>>>((const f4*)kb, (const f4*)kbp, mem_ws, v_ws, rai_ws);
    k_out<<<2048, 256, 0, stream>>>((const f4*)kb, rai_ws, (float*)d_out);
}

// Round 2
// 507.290 us; speedup vs baseline: 1.0764x; 1.0034x over previous
//
#include <hip/hip_runtime.h>
#include <hip/hip_bf16.h>

// ReadUnit: B=512, D=512, N=196
// rai[b,n] = sum_d p[b,d]*kbp[b,d,n] + q[b,d]*kb[b,d,n]   (+const_b, softmax-invariant)
//   p = (ms@Wmem^T + bmem) * v[:, :D],  q = v[:, D:],  v = (ctrl*Wattn) @ Wcat
// out[b,d] = sum_n softmax(rai)[n] * kb[b,d,n]
//
// v3: single fused kernel per batch. 512 blocks x 1024 threads (16 waves,
// VGPR<=64 -> 2 blocks/CU = 32 waves/CU, ALL blocks co-resident).
// Pass 1 streams kb+kbp (kbp nontemporal so L3 keeps kb; kb=205MB ~ fits 256MB
// L3). Block-level softmax. Pass 2 re-reads kb -> ~all L3 hits. Eliminates
// rai_ws round-trip, k_out launch, and its HBM re-fetch.

constexpr int D = 512;
constexpr int N = 196;
constexpr int NF4 = 49;  // N/4

using f4 = __attribute__((ext_vector_type(4))) float;

// ---------------- Phase A: two small fp32 GEMMs into workspace ----------------
__global__ __launch_bounds__(256) void phase_a(
    const float* __restrict__ ms, const float* __restrict__ ctrl,
    const float* __restrict__ Wmem, const float* __restrict__ bmem,
    const float* __restrict__ Wcat, const float* __restrict__ Wattn,
    float* __restrict__ mem_ws, float* __restrict__ v_ws)
{
    constexpr int PAD = 68;
    __shared__ float As[16 * PAD];
    __shared__ float Bs[16 * PAD];

    const int bid = blockIdx.x;
    const int t   = threadIdx.x;
    const int tx  = t & 15, ty = t >> 4;

    const bool g1 = (bid < 64);
    int tile_m, tile_n;
    if (g1) { tile_m = (bid >> 3) * 64; tile_n = (bid & 7) * 64; }
    else    { int bb = bid - 64; tile_m = (bb >> 4) * 64; tile_n = (bb & 15) * 64; }

    float acc[4][4] = {};

    for (int k0 = 0; k0 < 512; k0 += 16) {
        {
            const int k = t & 15;
            const int mbase = t >> 4;
#pragma unroll
            for (int r = 0; r < 4; r++) {
                const int m = mbase + 16 * r;
                const int row = tile_m + m;
                float a;
                if (g1) a = ms[row * 512 + k0 + k];
                else    a = ctrl[row * 512 + k0 + k] * Wattn[k0 + k];
                As[k * PAD + m] = a;
            }
        }
        if (g1) {
            const int k = t & 15;
            const int nbase = t >> 4;
#pragma unroll
            for (int r = 0; r < 4; r++) {
                const int n = nbase + 16 * r;
                Bs[k * PAD + n] = Wmem[(tile_n + n) * 512 + k0 + k];
            }
        } else {
            const int n = t & 63;
            const int kbase = t >> 6;
#pragma unroll
            for (int r = 0; r < 4; r++) {
                const int k = kbase + 4 * r;
                Bs[k * PAD + n] = Wcat[(k0 + k) * 1024 + tile_n + n];
            }
        }
        __syncthreads();
#pragma unroll
        for (int k = 0; k < 16; k++) {
            const float4 av = *reinterpret_cast<const float4*>(&As[k * PAD + ty * 4]);
            const float4 bv = *reinterpret_cast<const float4*>(&Bs[k * PAD + tx * 4]);
            const float a[4] = {av.x, av.y, av.z, av.w};
            const float bb[4] = {bv.x, bv.y, bv.z, bv.w};
#pragma unroll
            for (int i = 0; i < 4; i++)
#pragma unroll
                for (int j = 0; j < 4; j++)
                    acc[i][j] += a[i] * bb[j];
        }
        __syncthreads();
    }

    if (g1) {
#pragma unroll
        for (int i = 0; i < 4; i++) {
            const int row = tile_m + ty * 4 + i;
#pragma unroll
            for (int j = 0; j < 4; j++) {
                const int col = tile_n + tx * 4 + j;
                mem_ws[row * 512 + col] = acc[i][j] + bmem[col];
            }
        }
    } else {
#pragma unroll
        for (int i = 0; i < 4; i++) {
            const int row = tile_m + ty * 4 + i;
#pragma unroll
            for (int j = 0; j < 4; j++) {
                const int col = tile_n + tx * 4 + j;
                v_ws[row * 1024 + col] = acc[i][j];
            }
        }
    }
}

// ---------------- Fused: rai + softmax + weighted sum, one block per batch ----------------
// 1024 threads = 16 waves; wave w owns rows d = 32w..32w+31 in both passes.
// Lane l<49 owns float4-column l; each wave-instr reads one contiguous 784B row.
__global__ __launch_bounds__(1024, 8) void k_fused(
    const f4* __restrict__ kb, const f4* __restrict__ kbp,
    const float* __restrict__ mem_ws, const float* __restrict__ v_ws,
    float* __restrict__ out)
{
    __shared__ float p_s[D];
    __shared__ float q_s[D];
    __shared__ float part[16][200];
    __shared__ float w_s[200];
    __shared__ float red[16];
    __shared__ float out_s[D];

    const int b    = blockIdx.x;
    const int t    = threadIdx.x;
    const int lane = t & 63;
    const int w    = t >> 6;

    if (t < D) {
        p_s[t] = mem_ws[b * D + t] * v_ws[b * 2 * D + t];
        q_s[t] = v_ws[b * 2 * D + D + t];
    }
    __syncthreads();

    const int lc = (lane < NF4) ? lane : (NF4 - 1);  // lanes 49..63 dup col 48 (same cacheline)
    const f4* kb_b  = kb  + (size_t)b * (D * NF4);
    const f4* kbp_b = kbp + (size_t)b * (D * NF4);

    // ---- Pass 1: rai partials ----
    float a0 = 0.f, a1 = 0.f, a2 = 0.f, a3 = 0.f;
    const int dw = w * 32;  // each wave: 32 contiguous rows
#pragma unroll 4
    for (int r = 0; r < 32; r++) {
        const int d = dw + r;
        const f4 vp = __builtin_nontemporal_load(&kbp_b[(size_t)d * NF4 + lc]);
        const f4 vk = kb_b[(size_t)d * NF4 + lc];
        const float pd = p_s[d];
        const float qd = q_s[d];
        a0 += pd * vp.x + qd * vk.x;
        a1 += pd * vp.y + qd * vk.y;
        a2 += pd * vp.z + qd * vk.z;
        a3 += pd * vp.w + qd * vk.w;
    }

    if (lane < NF4) {
        part[w][4 * lane + 0] = a0;
        part[w][4 * lane + 1] = a1;
        part[w][4 * lane + 2] = a2;
        part[w][4 * lane + 3] = a3;
    }
    __syncthreads();

    // ---- Softmax over n (196) ----
    float e = 0.f;
    if (t < N) {
        float r = 0.f;
#pragma unroll
        for (int i = 0; i < 16; i++) r += part[i][t];
        e = __expf(r);           // rai is O(+-10): no max-subtraction needed in fp32
        w_s[t] = e;
    }
    float ssum = e;
#pragma unroll
    for (int m = 32; m; m >>= 1) ssum += __shfl_xor(ssum, m, 64);
    if (lane == 0) red[w] = ssum;
    __syncthreads();

    float tot = 0.f;
#pragma unroll
    for (int i = 0; i < 16; i++) tot += red[i];
    const float inv = 1.0f / tot;

    f4 wv = {0.f, 0.f, 0.f, 0.f};
    if (lane < NF4) {            // lanes >=49: wv=0 -> contribute 0 to reduction
        wv.x = w_s[4 * lane + 0] * inv;
        wv.y = w_s[4 * lane + 1] * inv;
        wv.z = w_s[4 * lane + 2] * inv;
        wv.w = w_s[4 * lane + 3] * inv;
    }

    // ---- Pass 2: weighted sum over n; kb rows just streamed -> L3-hot ----
#pragma unroll 4
    for (int r = 0; r < 32; r++) {
        const int d = dw + r;
        const f4 v = kb_b[(size_t)d * NF4 + lc];
        float sc = v.x * wv.x + v.y * wv.y + v.z * wv.z + v.w * wv.w;
#pragma unroll
        for (int m = 32; m; m >>= 1) sc += __shfl_xor(sc, m, 64);
        if (lane == 0) out_s[d] = sc;
    }
    __syncthreads();

    if (t < D) out[(size_t)b * D + t] = out_s[t];
}

extern "C" void kernel_launch(void* const* d_in, const int* in_sizes, int n_in,
                              void* d_out, int out_size, void* d_ws, size_t ws_size,
                              hipStream_t stream) {
    const float* ms    = (const float*)d_in[0];
    const float* kb    = (const float*)d_in[1];
    const float* ctrl  = (const float*)d_in[2];
    const float* kbp   = (const float*)d_in[3];
    const float* Wmem  = (const float*)d_in[4];
    const float* bmem  = (const float*)d_in[5];
    const float* Wcat  = (const float*)d_in[6];
    const float* Wattn = (const float*)d_in[8];

    float* mem_ws = (float*)d_ws;                 // 512*512
    float* v_ws   = mem_ws + 512 * 512;           // 512*1024

    phase_a<<<192, 256, 0, stream>>>(ms, ctrl, Wmem, bmem, Wcat, Wattn, mem_ws, v_ws);
    k_fused<<<512, 1024, 0, stream>>>((const f4*)kb, (const f4*)kbp, mem_ws, v_ws,
                                      (float*)d_out);
}